// Round 8
// baseline (1292.734 us; speedup 1.0000x reference)
//
#include <hip/hip_runtime.h>

#define N_NODES 100000
#define N_EDGES 1600000

#define BKT_SHIFT 8
#define BKT_NODES 256
#define NBK ((N_NODES + BKT_NODES - 1) / BKT_NODES)      // 391 buckets == chunks per slice
#define CHUNK 4096
#define NCHUNKS ((N_EDGES + CHUNK - 1) / CHUNK)          // 391 chunks
#define BCAP 6144
#define NSL 8                                            // channel slices
#define SCH 8                                            // channels per slice
#define SL_STRIDE ((size_t)N_NODES * SCH)                // floats per slice region

// ---------------- bucket-level histogram (391 bins) ----------------
__global__ __launch_bounds__(512) void bhist_kernel(const int* __restrict__ dst,
                                                    int* __restrict__ bhist) {
    __shared__ int h[NBK];
    for (int i = threadIdx.x; i < NBK; i += 512) h[i] = 0;
    __syncthreads();
    int stride = gridDim.x * 512;
    for (int e = blockIdx.x * 512 + threadIdx.x; e < N_EDGES; e += stride)
        atomicAdd(&h[dst[e] >> BKT_SHIFT], 1);
    __syncthreads();
    for (int i = threadIdx.x; i < NBK; i += 512) {
        int v = h[i];
        if (v) atomicAdd(&bhist[i], v);
    }
}

// ---------------- single-block scan of bucket histogram ----------------
__global__ __launch_bounds__(512) void scan_bhist_kernel(const int* __restrict__ bhist,
                                                         int* __restrict__ bbase,
                                                         int* __restrict__ bcursor) {
    __shared__ int s[512];
    int t = threadIdx.x;
    int v = (t < NBK) ? bhist[t] : 0;
    s[t] = v;
    __syncthreads();
    for (int off = 1; off < 512; off <<= 1) {
        int u = (t >= off) ? s[t - off] : 0;
        __syncthreads();
        s[t] += u;
        __syncthreads();
    }
    if (t < NBK) {
        int excl = s[t] - v;
        bbase[t] = excl;
        bcursor[t] = excl;
    }
    if (t == 0) bbase[NBK] = N_EDGES;
}

// ---------------- phase A: bin edges by 256-node bucket, coalesced runs ----------------
__global__ __launch_bounds__(512) void binA_kernel(const int* __restrict__ src,
                                                   const int* __restrict__ dst,
                                                   int* __restrict__ bcursor,
                                                   int2* __restrict__ csr_tmp) {
    __shared__ int2 staged[CHUNK];   // 32 KB
    __shared__ int delta[CHUNK];     // 16 KB
    __shared__ int hist[NBK];
    __shared__ int lcur[NBK];
    __shared__ int gdel[NBK];
    __shared__ int scan_s[512];
    int t = threadIdx.x;
    int e0 = blockIdx.x * CHUNK;
    int n = N_EDGES - e0; if (n > CHUNK) n = CHUNK;

    for (int i = t; i < NBK; i += 512) hist[i] = 0;
    __syncthreads();
    for (int i = t; i < n; i += 512) atomicAdd(&hist[dst[e0 + i] >> BKT_SHIFT], 1);
    __syncthreads();
    int v = (t < NBK) ? hist[t] : 0;
    scan_s[t] = v;
    __syncthreads();
    for (int off = 1; off < 512; off <<= 1) {
        int u = (t >= off) ? scan_s[t - off] : 0;
        __syncthreads();
        scan_s[t] += u;
        __syncthreads();
    }
    if (t < NBK) {
        int excl = scan_s[t] - v;
        lcur[t] = excl;
        int g = atomicAdd(&bcursor[t], v);
        gdel[t] = g - excl;
    }
    __syncthreads();
    for (int i = t; i < n; i += 512) {
        int s = src[e0 + i];
        int d = dst[e0 + i];
        int bkt = d >> BKT_SHIFT;
        int slot = atomicAdd(&lcur[bkt], 1);
        staged[slot] = make_int2(s, d);
        delta[slot] = gdel[bkt];
    }
    __syncthreads();
    for (int p = t; p < n; p += 512) csr_tmp[delta[p] + p] = staged[p];
}

// ---------------- phase B: per-bucket hist/scan/offs/dinv + exact CSR ordering ----------------
__global__ __launch_bounds__(256) void binB_kernel(const int* __restrict__ bbase,
                                                   const int2* __restrict__ csr_tmp,
                                                   int* __restrict__ offs,
                                                   float* __restrict__ dinv,
                                                   int* __restrict__ csr) {
    __shared__ int src_s[BCAP];
    __shared__ unsigned char dloc[BCAP];
    __shared__ int out_s[BCAP];
    __shared__ int lcnt[BKT_NODES];
    __shared__ int ss[BKT_NODES];
    __shared__ int lcur[BKT_NODES];
    int t = threadIdx.x;
    int node0 = blockIdx.x * BKT_NODES;
    int base = bbase[blockIdx.x];
    int cnt = bbase[blockIdx.x + 1] - base;
    lcnt[t] = 0;
    __syncthreads();
    bool fits = (cnt <= BCAP);
    if (fits) {
        for (int i = t; i < cnt; i += 256) {
            int2 e = csr_tmp[base + i];
            int dl = e.y - node0;
            src_s[i] = e.x;
            dloc[i] = (unsigned char)dl;
            atomicAdd(&lcnt[dl], 1);
        }
    } else {
        for (int i = t; i < cnt; i += 256) atomicAdd(&lcnt[csr_tmp[base + i].y - node0], 1);
    }
    __syncthreads();
    int v = lcnt[t];
    ss[t] = v;
    __syncthreads();
    for (int off = 1; off < 256; off <<= 1) {
        int u = (t >= off) ? ss[t - off] : 0;
        __syncthreads();
        ss[t] += u;
        __syncthreads();
    }
    int excl = ss[t] - v;
    lcur[t] = excl;
    int node = node0 + t;
    if (node < N_NODES) {
        offs[node] = base + excl;
        dinv[node] = rsqrtf((float)v + 1.0f);
    }
    if (blockIdx.x == NBK - 1 && t == 0) offs[N_NODES] = N_EDGES;
    __syncthreads();
    if (fits) {
        for (int i = t; i < cnt; i += 256) {
            int slot = atomicAdd(&lcur[dloc[i]], 1);
            out_s[slot] = src_s[i];
        }
        __syncthreads();
        for (int i = t; i < cnt; i += 256) csr[base + i] = out_s[i];
    } else {
        for (int i = t; i < cnt; i += 256) {
            int2 e = csr_tmp[base + i];
            int slot = atomicAdd(&lcur[e.y - node0], 1);
            csr[base + slot] = e.x;
        }
    }
}

// ---------------- prescale + re-slice: Xsl[s][n][c8] = X[n][s*8+c8] * dinv[n] ----------------
__global__ __launch_bounds__(256) void prescale_sliced_kernel(const float* __restrict__ X,
                                                              const float* __restrict__ dinv,
                                                              float* __restrict__ Xsl) {
    int i = blockIdx.x * 256 + threadIdx.x;
    if (i < N_NODES * 64) {
        int n = i >> 6, c = i & 63;
        float v = X[i] * dinv[n];
        Xsl[(size_t)(c >> 3) * SL_STRIDE + (size_t)n * SCH + (c & 7)] = v;
    }
}

// ---------------- XCD-pinned sliced gather ----------------
// A[n][s*8+c8] = dinv[n] * (Xsl[s][n][c8] + sum_{src in in(n)} Xsl[s][src][c8])
// Work = (chunk of 256 nodes, slice). Per-XCD queues + work stealing.
__global__ __launch_bounds__(256) void slice_gather_kernel(
    const float* __restrict__ Xsl, const float* __restrict__ dinv,
    const int* __restrict__ offs, const int* __restrict__ csr,
    float* __restrict__ A, int* __restrict__ qcnt, int pass) {
    __shared__ int sh_slice, sh_chunk;
    int t = threadIdx.x;
    int lane = t & 63;
    int wave = t >> 6;           // 0..3
    int sub = lane >> 3;         // 0..7: edge slot
    int ch = lane & 7;           // channel within slice

    int xcc;
    asm volatile("s_getreg_b32 %0, hwreg(HW_REG_XCC_ID)" : "=s"(xcc));
    xcc &= 7;

    for (;;) {
        if (t == 0) {
            sh_slice = -1;
            for (int step = 0; step < NSL; step++) {
                int sq = (xcc + step) & 7;
                int tk = atomicAdd(&qcnt[pass * NSL + sq], 1);
                if (tk < NBK) { sh_slice = sq; sh_chunk = tk; break; }
            }
        }
        __syncthreads();
        int slice = sh_slice;
        int chunk = sh_chunk;
        __syncthreads();
        if (slice < 0) break;

        const float* Xs = Xsl + (size_t)slice * SL_STRIDE;
        int n0 = chunk * BKT_NODES + wave * 64;
        int n1 = n0 + 64;
        if (n1 > N_NODES) n1 = N_NODES;
        for (int n = n0; n < n1; n++) {
            int beg = offs[n], end = offs[n + 1];
            float di = dinv[n];
            float acc = (sub == 0) ? Xs[(size_t)n * SCH + ch] : 0.0f;
            int iA = beg + sub, iB = iA + 8;
            int idxA = (iA < end) ? csr[iA] : n;
            int idxB = (iB < end) ? csr[iB] : n;
            float rA = Xs[(size_t)idxA * SCH + ch];
            while (iA < end) {
                float rB = Xs[(size_t)idxB * SCH + ch];
                int iC = iA + 16;
                int idxC = (iC < end) ? csr[iC] : n;
                acc += rA;
                rA = rB; idxB = idxC; iA = iB; iB = iC;
            }
            // reduce across 8 subs
            acc += __shfl_xor(acc, 8, 64);
            acc += __shfl_xor(acc, 16, 64);
            acc += __shfl_xor(acc, 32, 64);
            float a = acc * di;
            if (sub == 0) A[(size_t)n * 64 + slice * SCH + ch] = a;
        }
    }
}

// ---------------- dense transform: r = A[n] @ W + b ----------------
// mode 0: out_plain[n][c] = r
// mode 1: out_sliced[s][n][c8] = r * dinv[n]   (pre-scaled input for next layer)
__global__ __launch_bounds__(256) void gemm_kernel(const float* __restrict__ A,
                                                   const float* __restrict__ W,
                                                   const float* __restrict__ b,
                                                   const float* __restrict__ dinv,
                                                   float* __restrict__ outp,
                                                   int mode, int n_waves) {
    int lane = threadIdx.x & 63;
    int wid = (blockIdx.x * blockDim.x + threadIdx.x) >> 6;

    float wcol[64];
#pragma unroll
    for (int k = 0; k < 64; k++) wcol[k] = W[k * 64 + lane];
    float blane = b[lane];

    for (int node = wid; node < N_NODES; node += n_waves) {
        int ai = __float_as_int(A[(size_t)node * 64 + lane]);
        float r0 = 0.f, r1 = 0.f, r2 = 0.f, r3 = 0.f;
#pragma unroll
        for (int k = 0; k < 16; k++) {
            r0 = fmaf(__int_as_float(__builtin_amdgcn_readlane(ai, k)), wcol[k], r0);
            r1 = fmaf(__int_as_float(__builtin_amdgcn_readlane(ai, k + 16)), wcol[k + 16], r1);
            r2 = fmaf(__int_as_float(__builtin_amdgcn_readlane(ai, k + 32)), wcol[k + 32], r2);
            r3 = fmaf(__int_as_float(__builtin_amdgcn_readlane(ai, k + 48)), wcol[k + 48], r3);
        }
        float r = blane + ((r0 + r1) + (r2 + r3));
        if (mode == 0) {
            outp[(size_t)node * 64 + lane] = r;
        } else {
            float v = r * dinv[node];
            outp[(size_t)(lane >> 3) * SL_STRIDE + (size_t)node * SCH + (lane & 7)] = v;
        }
    }
}

extern "C" void kernel_launch(void* const* d_in, const int* in_sizes, int n_in,
                              void* d_out, int out_size, void* d_ws, size_t ws_size,
                              hipStream_t stream) {
    const float* emb = (const float*)d_in[0];
    const int* edge  = (const int*)d_in[1];
    const float* W1 = (const float*)d_in[2];
    const float* b1 = (const float*)d_in[3];
    const float* W2 = (const float*)d_in[4];
    const float* b2 = (const float*)d_in[5];
    const float* W3 = (const float*)d_in[6];
    const float* b3 = (const float*)d_in[7];
    float* out = (float*)d_out;

    const int* src = edge;
    const int* dst = edge + N_EDGES;

    char* ws = (char*)d_ws;
    size_t off = 0;
    int* bhist = (int*)(ws + off);      off += 2048;
    int* bbase = (int*)(ws + off);      off += 2048;     // NBK+1
    int* bcursor = (int*)(ws + off);    off += 2048;
    int* qcnt = (int*)(ws + off);       off += 2048;     // 3 passes × 8 queues
    int* offs = (int*)(ws + off);       off += 400128;   // N_NODES+1
    float* dinv = (float*)(ws + off);   off += 400128;
    int* csr = (int*)(ws + off);        off += 6400128;
    float* A = (float*)(ws + off);      off += 25600000; // aliases csr_tmp (build-then-use)
    int2* csr_tmp = (int2*)A;
    float* Xsl_a = (float*)(ws + off);  off += 25600000;
    float* Xsl_b = (float*)(ws + off);  // 25.6 MB

    // ---- CSR build (shared by all 3 layers) ----
    hipMemsetAsync(bhist, 0, NBK * sizeof(int), stream);
    hipMemsetAsync(qcnt, 0, 3 * NSL * sizeof(int), stream);
    bhist_kernel<<<64, 512, 0, stream>>>(dst, bhist);
    scan_bhist_kernel<<<1, 512, 0, stream>>>(bhist, bbase, bcursor);
    binA_kernel<<<NCHUNKS, 512, 0, stream>>>(src, dst, bcursor, csr_tmp);
    binB_kernel<<<NBK, 256, 0, stream>>>(bbase, csr_tmp, offs, dinv, csr);

    // Xsl_a = sliced(emb * dinv)
    prescale_sliced_kernel<<<(N_NODES * 64 + 255) / 256, 256, 0, stream>>>(emb, dinv, Xsl_a);

    const int SG_BLOCKS = 2048;               // 8 blocks/CU, persistent-queue driven
    const int GE_BLOCKS = 1024;
    const int ge_waves = GE_BLOCKS * 256 / 64;

    // layer 1
    slice_gather_kernel<<<SG_BLOCKS, 256, 0, stream>>>(Xsl_a, dinv, offs, csr, A, qcnt, 0);
    gemm_kernel<<<GE_BLOCKS, 256, 0, stream>>>(A, W1, b1, dinv, Xsl_b, 1, ge_waves);
    // layer 2
    slice_gather_kernel<<<SG_BLOCKS, 256, 0, stream>>>(Xsl_b, dinv, offs, csr, A, qcnt, 1);
    gemm_kernel<<<GE_BLOCKS, 256, 0, stream>>>(A, W2, b2, dinv, Xsl_a, 1, ge_waves);
    // layer 3
    slice_gather_kernel<<<SG_BLOCKS, 256, 0, stream>>>(Xsl_a, dinv, offs, csr, A, qcnt, 2);
    gemm_kernel<<<GE_BLOCKS, 256, 0, stream>>>(A, W3, b3, dinv, out, 0, ge_waves);
}